// Round 2
// baseline (142.767 us; speedup 1.0000x reference)
//
#include <hip/hip_runtime.h>

// Problem constants (fixed by the reference file).
#define T_LEN 8192
#define D_CH  2048

// v = z*v + x (x real), z complex. Two 2-deep FMA chains.
__device__ __forceinline__ void step_real(float zre, float zim,
                                          float& vre, float& vim, float x) {
    float nre = fmaf(zre, vre, fmaf(-zim, vim, x));
    float nim = fmaf(zre, vim, zim * vre);
    vre = nre; vim = nim;
}

__device__ __forceinline__ void load_z(const float* __restrict__ size_,
                                       const float* __restrict__ theta_,
                                       int d, float& zre, float& zim) {
    float e = expf(size_[d]);
    float r = expf(-e);
    float s, c;
    sincosf(theta_[d], &s, &c);
    zre = r * c;
    zim = r * s;
}

// Pass 1: per (chunk, channel-pair) local scan from v=0; write chunk-final values.
template <int CC>
__global__ __launch_bounds__(256) void k_local(const float* __restrict__ x,
                                               const float* __restrict__ size_,
                                               const float* __restrict__ theta_,
                                               float4* __restrict__ b) {
    constexpr int L = T_LEN / CC;
    const int dp = blockIdx.x * 256 + threadIdx.x;   // channel pair index
    const int d  = dp * 2;
    const int c  = blockIdx.y;

    float zre0, zim0, zre1, zim1;
    load_z(size_, theta_, d,     zre0, zim0);
    load_z(size_, theta_, d + 1, zre1, zim1);

    const float2* xp = (const float2*)x + (size_t)c * L * (D_CH / 2) + dp;
    float vre0 = 0.f, vim0 = 0.f, vre1 = 0.f, vim1 = 0.f;
#pragma unroll 8
    for (int k = 0; k < L; ++k) {
        float2 xv = xp[(size_t)k * (D_CH / 2)];
        step_real(zre0, zim0, vre0, vim0, xv.x);
        step_real(zre1, zim1, vre1, vim1, xv.y);
    }
    b[c * (D_CH / 2) + dp] = make_float4(vre0, vim0, vre1, vim1);
}

// Pass 2: per channel, exclusive scan over chunk summaries with z^L.
// In-place over b (viewed as float2 per (chunk, channel)).
template <int CC>
__global__ __launch_bounds__(256) void k_carry(const float* __restrict__ size_,
                                               const float* __restrict__ theta_,
                                               float2* __restrict__ b2) {
    constexpr int L = T_LEN / CC;
    const int d = blockIdx.x * 256 + threadIdx.x;
    float e  = expf(size_[d]);
    float th = theta_[d];
    // z^L = exp(-L*e) * (cos(L*th) + i sin(L*th)); underflow of rL -> 0 is correct.
    float rL = expf(-(float)L * e);
    float sL, cL;
    sincosf((float)L * th, &sL, &cL);
    const float zLre = rL * cL, zLim = rL * sL;

    float cre = 0.f, cim = 0.f;
    for (int base = 0; base < CC; base += 16) {
        float2 loc[16];
#pragma unroll
        for (int j = 0; j < 16; ++j)
            loc[j] = b2[(base + j) * D_CH + d];      // batch-issued loads
#pragma unroll
        for (int j = 0; j < 16; ++j) {
            b2[(base + j) * D_CH + d] = make_float2(cre, cim);
            float nre = fmaf(zLre, cre, fmaf(-zLim, cim, loc[j].x));
            float nim = fmaf(zLre, cim, fmaf(zLim, cre, loc[j].y));
            cre = nre; cim = nim;
        }
    }
}

// Pass 3: re-run local scan seeded with the carry; write output.
template <int CC, bool INTERLEAVED>
__global__ __launch_bounds__(256) void k_final(const float* __restrict__ x,
                                               const float* __restrict__ size_,
                                               const float* __restrict__ theta_,
                                               const float4* __restrict__ carry,
                                               float* __restrict__ out) {
    constexpr int L = T_LEN / CC;
    const int dp = blockIdx.x * 256 + threadIdx.x;
    const int d  = dp * 2;
    const int c  = blockIdx.y;

    float zre0, zim0, zre1, zim1;
    load_z(size_, theta_, d,     zre0, zim0);
    load_z(size_, theta_, d + 1, zre1, zim1);

    float4 cv = carry[c * (D_CH / 2) + dp];
    float vre0 = cv.x, vim0 = cv.y, vre1 = cv.z, vim1 = cv.w;
    const float2* xp = (const float2*)x + (size_t)c * L * (D_CH / 2) + dp;

    if (INTERLEAVED) {
        float4* o4 = (float4*)out;
#pragma unroll 8
        for (int k = 0; k < L; ++k) {
            float2 xv = xp[(size_t)k * (D_CH / 2)];
            step_real(zre0, zim0, vre0, vim0, xv.x);
            step_real(zre1, zim1, vre1, vim1, xv.y);
            o4[(size_t)(c * L + k) * (D_CH / 2) + dp] =
                make_float4(vre0, vim0, vre1, vim1);
        }
    } else {
        float2* o2 = (float2*)out;
#pragma unroll 8
        for (int k = 0; k < L; ++k) {
            float2 xv = xp[(size_t)k * (D_CH / 2)];
            step_real(zre0, zim0, vre0, vim0, xv.x);
            step_real(zre1, zim1, vre1, vim1, xv.y);
            o2[(size_t)(c * L + k) * (D_CH / 2) + dp] = make_float2(vre0, vre1);
        }
    }
}

template <int CC>
static void run_all(const float* x, const float* sz, const float* th,
                    void* d_out, int out_size, void* d_ws, hipStream_t stream) {
    float4* b  = (float4*)d_ws;                 // CC * D_CH * 8 bytes
    float2* b2 = (float2*)d_ws;
    dim3 blk(256);
    dim3 grid1(D_CH / 512, CC);                 // 2 channels per thread

    k_local<CC><<<grid1, blk, 0, stream>>>(x, sz, th, b);
    k_carry<CC><<<dim3(D_CH / 256), blk, 0, stream>>>(sz, th, b2);

    if (out_size == T_LEN * D_CH) {
        // Harness compares real part only as float32 [T, D].
        k_final<CC, false><<<grid1, blk, 0, stream>>>(x, sz, th, b, (float*)d_out);
    } else {
        // Full complex64 interleaved (re, im).
        k_final<CC, true><<<grid1, blk, 0, stream>>>(x, sz, th, b, (float*)d_out);
    }
}

extern "C" void kernel_launch(void* const* d_in, const int* in_sizes, int n_in,
                              void* d_out, int out_size, void* d_ws, size_t ws_size,
                              hipStream_t stream) {
    const float* x  = (const float*)d_in[0];
    const float* sz = (const float*)d_in[1];
    const float* th = (const float*)d_in[2];

    const size_t need256 = (size_t)256 * D_CH * 8;   // 4 MB
    if (ws_size >= need256) {
        run_all<256>(x, sz, th, d_out, out_size, d_ws, stream);
    } else {
        run_all<64>(x, sz, th, d_out, out_size, d_ws, stream);
    }
}